// Round 1
// baseline (30654.962 us; speedup 1.0000x reference)
//
// LSTM_45337674776685 — R1: correctness-first full pipeline.
// 2-layer LSTM scan: 32 persistent wgs (1 wave each), W_hh register-resident as
// bf16 hi/lo fragments, h@W via 3x mfma_f32_32x32x16_bf16 (emulated fp32).
// Cross-wg h exchange through device-scope atomics + monotone flags.
// Input-projection GEMMs (chunked) and head GEMMs in fp32 vector FMA.

#include <hip/hip_runtime.h>
#include <stdint.h>

typedef unsigned short u16;
typedef unsigned int   u32;
typedef unsigned long long u64;

typedef short  bf16x8 __attribute__((ext_vector_type(8)));
typedef float  f32x16 __attribute__((ext_vector_type(16)));

#define DEVI static __device__ __forceinline__

DEVI u16 f2bf(float x) {
  u32 u = __float_as_uint(x);
  u += 0x7FFFu + ((u >> 16) & 1u);
  return (u16)(u >> 16);
}
DEVI float bf2f(u16 h) { return __uint_as_float(((u32)h) << 16); }

DEVI float sig_fast(float x) {
  float d = 1.f + __expf(-x);
  float r = __builtin_amdgcn_rcpf(d);
  return r * (2.f - d * r);   // one NR step, ~0.5 ulp
}
DEVI float silu_f(float x) { return x * sig_fast(x); }

DEVI bf16x8 mk8(u64 a, u64 b) {
  union { u64 q[2]; bf16x8 v; } u;
  u.q[0] = a; u.q[1] = b;
  return u.v;
}

// ---------------------------------------------------------------------------
// prep: pack W_hh0/1 into MFMA B-fragments (bf16 hi/lo planes, gate-interleaved
// row permutation), combine biases, zero flags.
// frag layout: wf[layer][nt(32)][kt(16)][plane(2)][lane(64)][4 dwords]
// row perm: tile nt row rr (0..31): gate=rr&3, jj=rr>>2 -> r = gate*256+nt*8+jj
// k map (kappa, shared with A packing): k = kt*16 + (lane>>5)*8 + e
// ---------------------------------------------------------------------------
__global__ void k_prep(const float* __restrict__ Whh0, const float* __restrict__ Whh1,
                       const float* __restrict__ bih0, const float* __restrict__ bhh0,
                       const float* __restrict__ bih1, const float* __restrict__ bhh1,
                       u32* __restrict__ wf, float* __restrict__ biasc,
                       u32* __restrict__ flags)
{
  if (blockIdx.x < 256) {
    int g = blockIdx.x * 256 + threadIdx.x;      // [0, 65536)
    int layer = g >> 15;
    int nt = (g >> 10) & 31;
    int kt = (g >> 6) & 15;
    int l  = g & 63;
    int rr = l & 31, gate = rr & 3, jj = rr >> 2;
    int r  = gate * 256 + nt * 8 + jj;
    int k0 = kt * 16 + (l >> 5) * 8;
    const float* W = layer ? Whh1 : Whh0;        // (1024, 256) row-major
    float v[8];
    #pragma unroll
    for (int e = 0; e < 8; ++e) v[e] = W[(size_t)r * 256 + k0 + e];
    u32 hid[4], lod[4];
    #pragma unroll
    for (int p = 0; p < 4; ++p) {
      u16 h0 = f2bf(v[2 * p]), h1 = f2bf(v[2 * p + 1]);
      float l0 = v[2 * p] - bf2f(h0), l1 = v[2 * p + 1] - bf2f(h1);
      hid[p] = (u32)h0 | ((u32)h1 << 16);
      lod[p] = (u32)f2bf(l0) | ((u32)f2bf(l1) << 16);
    }
    size_t hoff = ((((size_t)(layer * 32 + nt) * 16 + kt) * 2 + 0) * 64 + l) * 4;
    size_t loff = hoff + 64 * 4;
    *(uint4*)(wf + hoff) = make_uint4(hid[0], hid[1], hid[2], hid[3]);
    *(uint4*)(wf + loff) = make_uint4(lod[0], lod[1], lod[2], lod[3]);
  } else {
    int t = threadIdx.x;
    for (int i = t; i < 1024; i += 256) flags[i] = 0;
    for (int i = t; i < 1024; i += 256) {
      biasc[i]        = bih0[i] + bhh0[i];
      biasc[1024 + i] = bih1[i] + bhh1[i];
    }
  }
}

// ---------------------------------------------------------------------------
// pack x (B,F,S) -> transposed bf16 hi/lo planes (B,S,F)
// ---------------------------------------------------------------------------
__global__ void k_packx(const float* __restrict__ x,
                        u16* __restrict__ xhi, u16* __restrict__ xlo)
{
  __shared__ float tile[64][65];
  const int s0 = blockIdx.x * 64;
  const int b  = blockIdx.y;
  const int t  = threadIdx.x;
  {
    int ss = t & 63, fq = t >> 6;
    #pragma unroll
    for (int r = 0; r < 16; ++r) {
      int f = fq * 16 + r;
      tile[f][ss] = x[((size_t)b * 64 + f) * 2048 + s0 + ss];
    }
  }
  __syncthreads();
  {
    int f2 = t & 63, sq = t >> 6;
    #pragma unroll
    for (int r = 0; r < 16; ++r) {
      int s = sq * 16 + r;
      float v = tile[f2][s];
      u16 hi = f2bf(v);
      u16 lo = f2bf(v - bf2f(hi));
      size_t o = ((size_t)b * 2048 + s0 + s) * 64 + f2;
      xhi[o] = hi; xlo[o] = lo;
    }
  }
}

// ---------------------------------------------------------------------------
// transpose P1 (B,S,64) f32 -> predT (B,64,S) f32
// ---------------------------------------------------------------------------
__global__ void k_transP(const float* __restrict__ P, float* __restrict__ PT)
{
  __shared__ float tile[64][65];
  const int s0 = blockIdx.x * 64;
  const int b  = blockIdx.y;
  const int t  = threadIdx.x;
  {
    int f = t & 63, sq = t >> 6;
    #pragma unroll
    for (int r = 0; r < 16; ++r) {
      int s = sq * 16 + r;
      tile[s][f] = P[((size_t)b * 2048 + s0 + s) * 64 + f];
    }
  }
  __syncthreads();
  {
    int s2 = t & 63, fq = t >> 6;
    #pragma unroll
    for (int r = 0; r < 16; ++r) {
      int ff = fq * 16 + r;
      PT[((size_t)b * 64 + ff) * 2048 + s0 + s2] = tile[s2][ff];
    }
  }
}

// ---------------------------------------------------------------------------
// generic fp32 TN GEMM: C[m][n] = act( sum_k A[m][k]*Bw[n][k] + bias[n] )
// A row = z*a_zrows + a_row0 + blockIdx.x*BM + r ; C row = z*c_zrows + same
// UA: A given as bf16 hi/lo planes (value = hi + lo).
// MODE 0: +bias ; 1: silu(+bias) ; 2: res + silu(+bias)
// ---------------------------------------------------------------------------
template<int BM, int BN, int TM, int TN, int MODE, int UA>
__global__ __launch_bounds__(256) void k_gemm(
    const float* __restrict__ Af,
    const u16* __restrict__ Ahi, const u16* __restrict__ Alo,
    const float* __restrict__ Bw,
    const float* __restrict__ bias,
    const float* __restrict__ res,
    float* __restrict__ C,
    int K, int lda,
    long a_zrows, long a_row0, long c_zrows, int ldc)
{
  constexpr int BK = 32;
  __shared__ float As[BK][BM + 4];
  __shared__ float Bs[BK][BN + 4];
  const int t  = threadIdx.x;
  const int tx = t & 15, ty = t >> 4;
  const int mb = blockIdx.x * BM, nb = blockIdx.y * BN;
  const long za = (long)blockIdx.z * a_zrows + a_row0 + mb;
  const long zc = (long)blockIdx.z * c_zrows + mb;

  float acc[TM][TN];
  #pragma unroll
  for (int i = 0; i < TM; ++i)
    #pragma unroll
    for (int jn = 0; jn < TN; ++jn) acc[i][jn] = 0.f;

  for (int k0 = 0; k0 < K; k0 += BK) {
    #pragma unroll
    for (int it = 0; it < BM * 8 / 256; ++it) {
      int idx = it * 256 + t;
      int row = idx >> 3, c4 = idx & 7;
      long ar = za + row;
      float v0, v1, v2, v3;
      if (UA) {
        u64 hh = *(const u64*)(Ahi + (size_t)ar * lda + k0 + c4 * 4);
        u64 ll = *(const u64*)(Alo + (size_t)ar * lda + k0 + c4 * 4);
        v0 = bf2f((u16)hh)         + bf2f((u16)ll);
        v1 = bf2f((u16)(hh >> 16)) + bf2f((u16)(ll >> 16));
        v2 = bf2f((u16)(hh >> 32)) + bf2f((u16)(ll >> 32));
        v3 = bf2f((u16)(hh >> 48)) + bf2f((u16)(ll >> 48));
      } else {
        float4 f4 = *(const float4*)(Af + (size_t)ar * lda + k0 + c4 * 4);
        v0 = f4.x; v1 = f4.y; v2 = f4.z; v3 = f4.w;
      }
      As[c4 * 4 + 0][row] = v0;
      As[c4 * 4 + 1][row] = v1;
      As[c4 * 4 + 2][row] = v2;
      As[c4 * 4 + 3][row] = v3;
    }
    #pragma unroll
    for (int it = 0; it < BN * 8 / 256; ++it) {
      int idx = it * 256 + t;
      int row = idx >> 3, c4 = idx & 7;
      float4 f4 = *(const float4*)(Bw + (size_t)(nb + row) * K + k0 + c4 * 4);
      Bs[c4 * 4 + 0][row] = f4.x;
      Bs[c4 * 4 + 1][row] = f4.y;
      Bs[c4 * 4 + 2][row] = f4.z;
      Bs[c4 * 4 + 3][row] = f4.w;
    }
    __syncthreads();
    #pragma unroll
    for (int kk = 0; kk < BK; ++kk) {
      float av[TM], bv[TN];
      {
        float4 t0 = *(const float4*)&As[kk][ty * TM];
        av[0] = t0.x; av[1] = t0.y; av[2] = t0.z; av[3] = t0.w;
        if (TM == 8) {
          float4 t1 = *(const float4*)&As[kk][ty * TM + 4];
          av[4] = t1.x; av[5] = t1.y; av[6] = t1.z; av[7] = t1.w;
        }
      }
      {
        float4 t0 = *(const float4*)&Bs[kk][tx * TN];
        bv[0] = t0.x; bv[1] = t0.y; bv[2] = t0.z; bv[3] = t0.w;
        if (TN == 8) {
          float4 t1 = *(const float4*)&Bs[kk][tx * TN + 4];
          bv[4] = t1.x; bv[5] = t1.y; bv[6] = t1.z; bv[7] = t1.w;
        }
      }
      #pragma unroll
      for (int i = 0; i < TM; ++i)
        #pragma unroll
        for (int jn = 0; jn < TN; ++jn)
          acc[i][jn] = fmaf(av[i], bv[jn], acc[i][jn]);
    }
    __syncthreads();
  }
  #pragma unroll
  for (int i = 0; i < TM; ++i) {
    long crow = zc + ty * TM + i;
    float* cp = C + (size_t)crow * ldc + nb + tx * TN;
    const float* rp = res + (size_t)crow * ldc + nb + tx * TN;
    #pragma unroll
    for (int jn = 0; jn < TN; ++jn) {
      float v = acc[i][jn] + bias[nb + tx * TN + jn];
      if (MODE == 1) v = silu_f(v);
      else if (MODE == 2) v = rp[jn] + silu_f(v);
      cp[jn] = v;
    }
  }
}

// ---------------------------------------------------------------------------
// persistent LSTM scan: 32 wgs x 64 threads. Wave nt owns permuted gate rows
// [i,f,g,o]x8j of its j-slice. Per step: 48 MFMAs (bf16x3), wave-local cell
// update via small LDS transpose, publish h (bf16 hi/lo) + release flag.
// ---------------------------------------------------------------------------
__global__ __launch_bounds__(64) void k_scan(
    const u32* __restrict__ wf,
    const float* __restrict__ xg,          // [B][cs][1024]
    u16* __restrict__ hbhi, u16* __restrict__ hblo,   // [2][32][256]
    u32* __restrict__ flags,               // 32 flags, stride 16 u32
    float* __restrict__ cbuf,              // [32][256]
    u16* __restrict__ histhi, u16* __restrict__ histlo, // [B][2048][256]
    int t0, int t1, int cs)
{
  const int nt  = blockIdx.x;
  const int l   = threadIdx.x;
  const int rr  = l & 31;
  const int hi5 = l >> 5;
  const int gate = rr & 3;
  const int jj   = rr >> 2;
  const int q    = l & 3;
  const int j    = nt * 8 + jj;
  const int rorig = gate * 256 + nt * 8 + jj;
  const bool isg = (gate == 2);

  bf16x8 wh[16], wl[16];
  {
    const u32* p = wf + (size_t)nt * (16 * 2 * 64 * 4);
    #pragma unroll
    for (int kt = 0; kt < 16; ++kt) {
      union { uint4 u; bf16x8 v; } ua, ub;
      ua.u = *(const uint4*)(p + ((size_t)(kt * 2 + 0) * 64 + l) * 4);
      ub.u = *(const uint4*)(p + ((size_t)(kt * 2 + 1) * 64 + l) * 4);
      wh[kt] = ua.v; wl[kt] = ub.v;
    }
  }

  float c4v[4];
  if (t0 == 0) {
    c4v[0] = c4v[1] = c4v[2] = c4v[3] = 0.f;
  } else {
    #pragma unroll
    for (int ri = 0; ri < 4; ++ri)
      c4v[ri] = cbuf[(size_t)(8 * q + 4 * hi5 + ri) * 256 + j];
  }

  __shared__ __align__(16) float zex[2][16][36];

  for (int t = t0; t < t1; ++t) {
    // xg loads for this step (D-layout batches per reg), issued early
    float xgv[16];
    #pragma unroll
    for (int reg = 0; reg < 16; ++reg) {
      int b = (reg & 3) + 8 * (reg >> 2) + 4 * hi5;
      xgv[reg] = xg[((size_t)b * cs + (t - t0)) * 1024 + rorig];
    }

    f32x16 acc = {};
    if (t > 0) {
      {
        const u32 tgt = (u32)t;
        int guard = 0;
        while (true) {
          u32 fv = __hip_atomic_load(&flags[(l & 31) * 16],
                                     __ATOMIC_ACQUIRE, __HIP_MEMORY_SCOPE_AGENT);
          if (__all((int)(fv >= tgt))) break;
          if (++guard > 4096) break;    // safety: never hang the bench
          __builtin_amdgcn_s_sleep(1);
        }
      }
      const u16* bh = hbhi + (size_t)(t & 1) * (32 * 256);
      const u16* bl = hblo + (size_t)(t & 1) * (32 * 256);
      const size_t abase = (size_t)(l & 31) * 256 + hi5 * 8;
      f32x16 aA = {}, aB = {}, aC = {};
      #pragma unroll
      for (int kt = 0; kt < 16; ++kt) {
        size_t o = abase + kt * 16;
        u64 h0 = __hip_atomic_load((const u64*)(bh + o),     __ATOMIC_RELAXED, __HIP_MEMORY_SCOPE_AGENT);
        u64 h1 = __hip_atomic_load((const u64*)(bh + o + 4), __ATOMIC_RELAXED, __HIP_MEMORY_SCOPE_AGENT);
        u64 g0 = __hip_atomic_load((const u64*)(bl + o),     __ATOMIC_RELAXED, __HIP_MEMORY_SCOPE_AGENT);
        u64 g1 = __hip_atomic_load((const u64*)(bl + o + 4), __ATOMIC_RELAXED, __HIP_MEMORY_SCOPE_AGENT);
        bf16x8 ah = mk8(h0, h1);
        bf16x8 al = mk8(g0, g1);
        aA = __builtin_amdgcn_mfma_f32_32x32x16_bf16(ah, wh[kt], aA, 0, 0, 0);
        aB = __builtin_amdgcn_mfma_f32_32x32x16_bf16(al, wh[kt], aB, 0, 0, 0);
        aC = __builtin_amdgcn_mfma_f32_32x32x16_bf16(ah, wl[kt], aC, 0, 0, 0);
      }
      acc = (aA + aB) + aC;
    }

    __syncthreads();
    #pragma unroll
    for (int reg = 0; reg < 16; ++reg) {
      float pre = acc[reg] + xgv[reg];
      float s = isg ? (2.f * pre) : pre;
      float y = sig_fast(s);                       // own gate activation
      zex[hi5][reg][rr] = isg ? (2.f * y - 1.f) : y; // tanh = 2*sig(2x)-1
    }
    __syncthreads();

    u16* dh = hbhi + (size_t)((t + 1) & 1) * (32 * 256);
    u16* dl = hblo + (size_t)((t + 1) & 1) * (32 * 256);
    #pragma unroll
    for (int ri = 0; ri < 4; ++ri) {
      const float4 gv = *(const float4*)&zex[hi5][q * 4 + ri][jj * 4]; // i,f,g,o
      float cn = fmaf(gv.y, c4v[ri], gv.x * gv.z);
      c4v[ri] = cn;
      float th = 2.f * sig_fast(2.f * cn) - 1.f;
      float hv = gv.w * th;
      u16 sh = f2bf(hv);
      u16 sl = f2bf(hv - bf2f(sh));
      int b = 8 * q + 4 * hi5 + ri;
      __hip_atomic_store(dh + (size_t)b * 256 + j, sh, __ATOMIC_RELAXED, __HIP_MEMORY_SCOPE_AGENT);
      __hip_atomic_store(dl + (size_t)b * 256 + j, sl, __ATOMIC_RELAXED, __HIP_MEMORY_SCOPE_AGENT);
      size_t ho = ((size_t)b * 2048 + t) * 256 + j;
      histhi[ho] = sh;
      histlo[ho] = sl;
    }
    if (l == 0)
      __hip_atomic_store(&flags[nt * 16], (u32)(t + 1),
                         __ATOMIC_RELEASE, __HIP_MEMORY_SCOPE_AGENT);
  }
  #pragma unroll
  for (int ri = 0; ri < 4; ++ri)
    cbuf[(size_t)(8 * q + 4 * hi5 + ri) * 256 + j] = c4v[ri];
}

// ---------------------------------------------------------------------------
// softmax over rows of 2048
// ---------------------------------------------------------------------------
__global__ __launch_bounds__(256) void k_softmax(const float* __restrict__ X,
                                                 float* __restrict__ O)
{
  __shared__ float red[256];
  const int t = threadIdx.x;
  const size_t row = blockIdx.x;
  const float* xr = X + row * 2048;
  float v[8];
  {
    float4 va = *(const float4*)(xr + t * 8);
    float4 vb = *(const float4*)(xr + t * 8 + 4);
    v[0]=va.x; v[1]=va.y; v[2]=va.z; v[3]=va.w;
    v[4]=vb.x; v[5]=vb.y; v[6]=vb.z; v[7]=vb.w;
  }
  float m = v[0];
  #pragma unroll
  for (int i = 1; i < 8; ++i) m = fmaxf(m, v[i]);
  red[t] = m; __syncthreads();
  for (int s = 128; s > 0; s >>= 1) {
    if (t < s) red[t] = fmaxf(red[t], red[t + s]);
    __syncthreads();
  }
  m = red[0];
  __syncthreads();
  float sum = 0.f;
  #pragma unroll
  for (int i = 0; i < 8; ++i) { v[i] = __expf(v[i] - m); sum += v[i]; }
  red[t] = sum; __syncthreads();
  for (int s = 128; s > 0; s >>= 1) {
    if (t < s) red[t] += red[t + s];
    __syncthreads();
  }
  const float inv = 1.f / red[0];
  float* op = O + row * 2048 + t * 8;
  float4 oa = { v[0]*inv, v[1]*inv, v[2]*inv, v[3]*inv };
  float4 ob = { v[4]*inv, v[5]*inv, v[6]*inv, v[7]*inv };
  *(float4*)op = oa;
  *(float4*)(op + 4) = ob;
}

// ---------------------------------------------------------------------------
extern "C" void kernel_launch(void* const* d_in, const int* in_sizes, int n_in,
                              void* d_out, int out_size, void* d_ws, size_t ws_size,
                              hipStream_t stream)
{
  const float* x    = (const float*)d_in[0];
  const float* Wih0 = (const float*)d_in[1];
  const float* Whh0 = (const float*)d_in[2];
  const float* bih0 = (const float*)d_in[3];
  const float* bhh0 = (const float*)d_in[4];
  const float* Wih1 = (const float*)d_in[5];
  const float* Whh1 = (const float*)d_in[6];
  const float* bih1 = (const float*)d_in[7];
  const float* bhh1 = (const float*)d_in[8];
  const float* W1   = (const float*)d_in[9];
  const float* b1   = (const float*)d_in[10];
  const float* W1b  = (const float*)d_in[11];
  const float* b1b  = (const float*)d_in[12];
  const float* W2   = (const float*)d_in[13];
  const float* b2   = (const float*)d_in[14];
  const float* W2b  = (const float*)d_in[15];
  const float* b2b  = (const float*)d_in[16];
  (void)in_sizes; (void)n_in;

  const size_t PL = (size_t)32 * 2048 * 256 * 2;      // one h plane: 33.55MB
  const size_t XT = (size_t)32 * 2048 * 64 * 2;       // one x plane: 8.39MB
  const size_t WF = (size_t)2 * 32 * 16 * 2 * 64 * 16; // 2MB frags

  auto need = [&](int c) -> size_t {
    return (size_t)32 * c * 1024 * 4 + 4 * PL + 2 * XT + WF + (1u << 20);
  };
  int cs = 512;
  while (cs > 128 && need(cs) > ws_size) cs >>= 1;
  if (need(cs) > ws_size) {   // distinctive signature: huge absmax
    hipMemsetAsync(d_out, 0x7F, (size_t)out_size * 4, stream);
    return;
  }

  char* w = (char*)d_ws;
  size_t off = 0;
  auto take = [&](size_t bytes) {
    size_t r = off;
    off = (off + bytes + 255) & ~(size_t)255;
    return r;
  };
  size_t o_xg   = take((size_t)32 * cs * 1024 * 4);
  size_t o_h0hi = take(PL), o_h0lo = take(PL);
  size_t o_h1hi = take(PL), o_h1lo = take(PL);
  size_t o_xthi = take(XT), o_xtlo = take(XT);
  size_t o_wf   = take(WF);
  size_t o_bias = take(8192);
  size_t o_hbhi = take(2 * 32 * 256 * 2);
  size_t o_hblo = take(2 * 32 * 256 * 2);
  size_t o_flag = take(4096);
  size_t o_cbuf = take(32 * 256 * 4);

  float* xg    = (float*)(w + o_xg);
  u16*   h0hi  = (u16*)(w + o_h0hi);
  u16*   h0lo  = (u16*)(w + o_h0lo);
  u16*   h1hi  = (u16*)(w + o_h1hi);
  u16*   h1lo  = (u16*)(w + o_h1lo);
  u16*   xthi  = (u16*)(w + o_xthi);
  u16*   xtlo  = (u16*)(w + o_xtlo);
  u32*   wf    = (u32*)(w + o_wf);
  float* biasc = (float*)(w + o_bias);
  u16*   hbhi  = (u16*)(w + o_hbhi);
  u16*   hblo  = (u16*)(w + o_hblo);
  u32*   flags = (u32*)(w + o_flag);
  float* cbuf  = (float*)(w + o_cbuf);
  // overlays (regions dead by the time they're written):
  float* P0    = (float*)(w + o_h0hi);
  float* P1    = (float*)(w + o_h0hi + 16777216);
  float* predT = (float*)(w + o_h0lo);
  float* out1  = (float*)(w + o_h0lo + 16777216);
  float* out2  = (float*)(w + o_h1hi);

  k_prep<<<257, 256, 0, stream>>>(Whh0, Whh1, bih0, bhh0, bih1, bhh1,
                                  wf, biasc, flags);
  k_packx<<<dim3(32, 32), 256, 0, stream>>>(x, xthi, xtlo);

  const int Q = 2048 / cs;
  // layer 0
  for (int qq = 0; qq < Q; ++qq) {
    k_gemm<128, 128, 8, 8, 0, 1><<<dim3(cs / 128, 8, 32), 256, 0, stream>>>(
        nullptr, xthi, xtlo, Wih0, biasc, xg, xg,
        64, 64, 2048, (long)qq * cs, cs, 1024);
    k_scan<<<32, 64, 0, stream>>>(wf, xg, hbhi, hblo, flags, cbuf,
                                  h0hi, h0lo, qq * cs, (qq + 1) * cs, cs);
  }
  // layer 1
  for (int qq = 0; qq < Q; ++qq) {
    k_gemm<128, 128, 8, 8, 0, 1><<<dim3(cs / 128, 8, 32), 256, 0, stream>>>(
        nullptr, h0hi, h0lo, Wih1, biasc + 1024, xg, xg,
        256, 256, 2048, (long)qq * cs, cs, 1024);
    k_scan<<<32, 64, 0, stream>>>(wf + (size_t)32 * 16 * 2 * 64 * 4, xg,
                                  hbhi, hblo, flags + 512, cbuf,
                                  h1hi, h1lo, qq * cs, (qq + 1) * cs, cs);
  }
  // heads
  k_gemm<128, 64, 8, 4, 1, 1><<<dim3(512, 1, 1), 256, 0, stream>>>(
      nullptr, h1hi, h1lo, W1, b1, P0, P0, 256, 256, 0, 0, 0, 64);
  k_gemm<128, 64, 8, 4, 2, 0><<<dim3(512, 1, 1), 256, 0, stream>>>(
      P0, nullptr, nullptr, W1b, b1b, P0, P1, 64, 64, 0, 0, 0, 64);
  k_transP<<<dim3(32, 32), 256, 0, stream>>>(P1, predT);
  k_gemm<128, 128, 8, 8, 0, 0><<<dim3(16, 16, 1), 256, 0, stream>>>(
      predT, nullptr, nullptr, W2, b2, out1, out1, 2048, 2048, 0, 0, 0, 2048);
  k_gemm<128, 128, 8, 8, 2, 0><<<dim3(16, 16, 1), 256, 0, stream>>>(
      out1, nullptr, nullptr, W2b, b2b, out1, out2, 2048, 2048, 0, 0, 0, 2048);
  k_softmax<<<2048, 256, 0, stream>>>(out2, (float*)d_out);
}